// Round 11
// baseline (198.721 us; speedup 1.0000x reference)
//
#include <hip/hip_runtime.h>
#include <hip/hip_bf16.h>

// B=2, S=2048, D=1024, H=16, DH=64. fp32 in/out; bf16 MFMA internals.
#define S_LEN   2048
#define D_MODEL 1024
#define N_HEADS 16
#define D_HEAD  64
#define HEAD_ELEMS (2048ull * 64ull)          // elements per (b,h) plane
#define MAT_ELEMS  (4096ull * 1024ull)        // one projected matrix (Q/K/V)
#define W_ELEMS    (1024ull * 1024ull)        // one weight matrix

typedef __attribute__((ext_vector_type(8))) short short8_t;   // 8 bf16
typedef __attribute__((ext_vector_type(4))) short short4_t;   // 4 bf16
typedef __attribute__((ext_vector_type(4))) float f32x4;      // MFMA C/D frag

__device__ __forceinline__ short f2bf(float f) {
    __hip_bfloat16 h = __float2bfloat16(f);
    union { __hip_bfloat16 h; short s; } cv;
    cv.h = h;
    return cv.s;
}

// global_load_lds width=16: LDS dest = wave-uniform base + lane*16
#define GLD_LDS16(gptr, lptr) \
    __builtin_amdgcn_global_load_lds( \
        (const __attribute__((address_space(1))) unsigned int*)(gptr), \
        (__attribute__((address_space(3))) unsigned int*)(lptr), 16, 0, 0)

// ---------------------------------------------------------------------------
// Kernel 0a: convert x fp32 -> bf16.
// ---------------------------------------------------------------------------
__global__ __launch_bounds__(256) void convert_x_kernel(
    const float* __restrict__ x, short* __restrict__ xb)
{
    const int i = (blockIdx.x * 256 + threadIdx.x) * 8;
    const float4 v0 = *(const float4*)(x + i);
    const float4 v1 = *(const float4*)(x + i + 4);
    short8_t u;
    u[0] = f2bf(v0.x); u[1] = f2bf(v0.y); u[2] = f2bf(v0.z); u[3] = f2bf(v0.w);
    u[4] = f2bf(v1.x); u[5] = f2bf(v1.y); u[6] = f2bf(v1.z); u[7] = f2bf(v1.w);
    *(short8_t*)(xb + i) = u;
}

// ---------------------------------------------------------------------------
// Kernel 0b: convert + transpose W fp32[k][n] -> bf16 Wt[n][k].
// ---------------------------------------------------------------------------
__global__ __launch_bounds__(256) void transpose_w_kernel(
    const float* __restrict__ Wq, const float* __restrict__ Wk,
    const float* __restrict__ Wv, short* __restrict__ wt)
{
    const int k0 = blockIdx.x * 64;
    const int n0 = blockIdx.y * 64;
    const int which = blockIdx.z;
    const float* W = (which == 0) ? Wq : (which == 1) ? Wk : Wv;
    short* out = wt + (size_t)which * W_ELEMS;

    __shared__ float Ts[64][68];   // [n_local][k_local]
    const int t = threadIdx.x;
    {
        const int c4 = (t & 15) * 4;
#pragma unroll
        for (int i = 0; i < 4; ++i) {
            const int r = (t >> 4) + i * 16;
            const float4 v = *(const float4*)(W + (size_t)(k0 + r) * D_MODEL + n0 + c4);
            Ts[c4 + 0][r] = v.x; Ts[c4 + 1][r] = v.y;
            Ts[c4 + 2][r] = v.z; Ts[c4 + 3][r] = v.w;
        }
    }
    __syncthreads();
    const int nl = t >> 2;
#pragma unroll
    for (int s = 0; s < 2; ++s) {
        const int koff = (t & 3) * 8 + s * 32;
        short8_t u;
#pragma unroll
        for (int j = 0; j < 8; ++j) u[j] = f2bf(Ts[nl][koff + j]);
        *(short8_t*)(out + (size_t)(n0 + nl) * D_MODEL + k0 + koff) = u;
    }
}

// ---------------------------------------------------------------------------
// Kernel 1: QKV GEMM (m97 structure). Q pre-scaled by (1/8)*log2(e) so the
// attention softmax can run in exp2 domain. Q/K and V epilogues round-trip
// through wave-private LDS for coalesced dwordx4 stores.
// ---------------------------------------------------------------------------
__global__ __launch_bounds__(256, 3) void qkv_mfma_gemm_kernel(
    const short* __restrict__ xb,
    const short* __restrict__ wt,
    short* __restrict__ qkv)
{
    const int mBlock = blockIdx.x * 128;
    const int nBlock = blockIdx.y * 128;
    const int which  = blockIdx.z;
    const short* Bt = wt + (size_t)which * W_ELEMS;
    short* outBase  = qkv + (size_t)which * MAT_ELEMS;

    __shared__ short As[128 * 32];               // [m][k] contiguous, 8 KB
    __shared__ short Bs[128 * 32];               // [n][k] contiguous, 8 KB
    __shared__ __align__(16) short Es[4][64 * 72]; // per-wave epilogue, 36 KB

    const int t    = threadIdx.x;
    const int w    = t >> 6;
    const int lane = t & 63;
    const int n16  = lane & 15;
    const int quad = lane >> 4;
    const int mq   = (w & 1) * 64;
    const int nq   = (w >> 1) * 64;

    f32x4 acc[4][4];
#pragma unroll
    for (int i = 0; i < 4; ++i)
#pragma unroll
        for (int j = 0; j < 4; ++j) acc[i][j] = (f32x4){0.f, 0.f, 0.f, 0.f};

    const int off0 = w * 2048 + lane * 16;       // bytes
    const int off1 = off0 + 1024;
    const int r0s = off0 >> 6, k0s = (off0 & 63) >> 1;
    const int r1s = off1 >> 6, k1s = (off1 & 63) >> 1;
    const short* gA0 = xb + (size_t)(mBlock + r0s) * D_MODEL + k0s;
    const short* gA1 = xb + (size_t)(mBlock + r1s) * D_MODEL + k1s;
    const short* gB0 = Bt + (size_t)(nBlock + r0s) * D_MODEL + k0s;
    const short* gB1 = Bt + (size_t)(nBlock + r1s) * D_MODEL + k1s;
    short* lA0 = As + w * 1024;
    short* lA1 = As + w * 1024 + 512;
    short* lB0 = Bs + w * 1024;
    short* lB1 = Bs + w * 1024 + 512;

    for (int k0 = 0; k0 < D_MODEL; k0 += 32) {
        __syncthreads();
        GLD_LDS16(gA0 + k0, lA0);
        GLD_LDS16(gA1 + k0, lA1);
        GLD_LDS16(gB0 + k0, lB0);
        GLD_LDS16(gB1 + k0, lB1);
        __syncthreads();

        short8_t af[4], bf[4];
#pragma unroll
        for (int mt = 0; mt < 4; ++mt)
            af[mt] = *(const short8_t*)&As[(mq + mt * 16 + n16) * 32 + quad * 8];
#pragma unroll
        for (int nt = 0; nt < 4; ++nt)
            bf[nt] = *(const short8_t*)&Bs[(nq + nt * 16 + n16) * 32 + quad * 8];
#pragma unroll
        for (int mt = 0; mt < 4; ++mt)
#pragma unroll
            for (int nt = 0; nt < 4; ++nt)
                acc[mt][nt] = __builtin_amdgcn_mfma_f32_16x16x32_bf16(
                    af[mt], bf[nt], acc[mt][nt], 0, 0, 0);
    }

    // fold 1/sqrt(DH) AND log2(e) into Q (softmax runs in exp2 domain)
    const float oscale = (which == 0) ? 0.125f * 1.44269504089f : 1.0f;
    short* E = &Es[w][0];
    const int h  = (nBlock + nq) >> 6;           // head: fixed per wave tile
    const int m0 = mBlock + mq;                  // 64-aligned
    const int bb = m0 >> 11, ss0 = m0 & 2047;    // tile never crosses b
    const int rsub = lane >> 3;                  // 0..7
    const int ch   = lane & 7;                   // 0..7 (16B chunk)

    if (which < 2) {
        // ---- stage bf16 tile in wave-private LDS [s_local][dh], pad 72 ----
#pragma unroll
        for (int mt = 0; mt < 4; ++mt)
#pragma unroll
            for (int nt = 0; nt < 4; ++nt) {
                const int dhl = nt * 16 + n16;
#pragma unroll
                for (int reg = 0; reg < 4; ++reg) {
                    const int ml = mt * 16 + quad * 4 + reg;
                    E[ml * 72 + dhl] = f2bf(acc[mt][nt][reg] * oscale);
                }
            }
        // wave-private: no barrier needed; lgkmcnt orders write->read
        short* orow = outBase + ((size_t)(bb * N_HEADS + h) * S_LEN + ss0) * D_HEAD
                      + ch * 8;
#pragma unroll
        for (int it = 0; it < 8; ++it) {
            const int row = it * 8 + rsub;       // s_local
            const short8_t v = *(const short8_t*)&E[row * 72 + ch * 8];
            *(short8_t*)(orow + (size_t)row * D_HEAD) = v;
        }
    } else {
        // ---- V transposed (b,h,dh,s): stage [dh_local][s_local], pad 72 ----
#pragma unroll
        for (int mt = 0; mt < 4; ++mt)
#pragma unroll
            for (int nt = 0; nt < 4; ++nt) {
                const int dhl = nt * 16 + n16;
                const int sl0 = mt * 16 + quad * 4;
                short4_t u;
                u[0] = f2bf(acc[mt][nt][0]); u[1] = f2bf(acc[mt][nt][1]);
                u[2] = f2bf(acc[mt][nt][2]); u[3] = f2bf(acc[mt][nt][3]);
                *(short4_t*)&E[dhl * 72 + sl0] = u;
            }
        // coalesced: 8 lanes x 16B = 128B contiguous in s per dh-row
        short* orow = outBase + ((size_t)(bb * N_HEADS + h) * D_HEAD) * S_LEN
                      + ss0 + ch * 8;
#pragma unroll
        for (int it = 0; it < 8; ++it) {
            const int dhl = it * 8 + rsub;       // dh_local 0..63
            const short8_t v = *(const short8_t*)&E[dhl * 72 + ch * 8];
            *(short8_t*)(orow + (size_t)dhl * S_LEN) = v;
        }
    }
}

// ---------------------------------------------------------------------------
// Kernel 2: causal flash attention via bf16 MFMA, v15.
// DS-pipe accounting across 11 variants: per tile ~1088 DS cycles (K reads
// 384 + V reads 384 + staging writes 128 + Ps 192) at ~68% DS utilization is
// the binder. v14 (in-lane P) raised MfmaUtil but b64 V reads tripled bank
// conflicts — net loss. v15 attacks the other big DS consumer:
//   V IS NOT STAGED. V fragments are read directly from global (L2-resident)
//   with the 8 loads issued at the TOP of the tile body — their ~200-400cy
//   L2 latency hides under QK+softmax (~1.5-2k cy). Address formula is v2's,
//   HW-validated (v5 passed). DS/tile drops ~41%; V staging ops and all
//   V-read LDS conflicts disappear. +32 VGPR live (va[8]) -> ~100, fits
//   (512,4). K staging unchanged (feeds QK immediately -> must stage).
// Everything else byte-identical to banked R6 best (v7): two 4-wave groups,
// 2 tiles/round, staged XOR-swizzled K, Ps LDS roundtrip, exp2 softmax,
// defer-max, setprio, flash-decoding merge, paired LPT grid.
// ---------------------------------------------------------------------------
__global__ __launch_bounds__(512, 4) void attn_mfma_kernel(
    const short* __restrict__ qkv,
    float* __restrict__ out)
{
    const int bh   = blockIdx.x;
    const int pr   = blockIdx.y;          // pair index 0..15
    const int t    = threadIdx.x;         // 0..511
    const int w    = t >> 6;              // 0..7
    const int g    = w >> 2;              // tile-group 0/1
    const int wl   = w & 3;               // wave-in-group 0..3
    const int lane = t & 63;
    const int n    = lane & 15;
    const int quad = lane >> 4;

    const short* Q  = qkv + (size_t)bh * HEAD_ELEMS;
    const short* K  = qkv + MAT_ELEMS + (size_t)bh * HEAD_ELEMS;
    const short* Vt = qkv + 2 * MAT_ELEMS + (size_t)bh * HEAD_ELEMS;  // (dh,s)

    __shared__ __align__(16) short Ks[2][64 * 64];       // per-group K, 16 KB
    __shared__ __align__(16) short Vs[2][64 * 64];       // merge scratch, 16 KB
    __shared__ __align__(16) short Ps[8][16][72];        // per-wave P round-trip
    __shared__ float Ml[2][64];                          // per-group m partial
    __shared__ float Ll[2][64];                          // per-group l partial

    // --- staging: group-wave wl stages rows [16wl,16wl+16) of K only ---
    const int srow0 = wl * 16 + (lane >> 3);             // inst-0 row
    const int srow1 = srow0 + 8;                         // inst-1 row
    const int sd0 = ((lane & 7) ^ (srow0 & 7)) * 8;      // swizzled src offset
    const int sd1 = ((lane & 7) ^ (srow1 & 7)) * 8;
    const short* gK0 = K + srow0 * 64 + sd0;             // += j0*64 per tile
    const short* gK1 = K + srow1 * 64 + sd1;
    short* lK0 = &Ks[g][(wl * 16) * 64];
    short* lK1 = &Ks[g][(wl * 16 + 8) * 64];

    // per-lane V global base: row dh = f*16+n, keys j0+quad*8 (+32)
    const short* vbase = Vt + (size_t)n * S_LEN + quad * 8;

    // K frag-read physical chunk offset (shorts): a0 at pcK, a1 at pcK^32
    const int pcK = ((quad ^ (n & 7))) * 8;

    const int bb = bh >> 4;
    const int hh = bh & 15;

    for (int pass = 0; pass < 2; ++pass) {
        const int qb = pass ? (31 - pr) : pr;
        const int r0 = qb * 64 + wl * 16;      // both groups cover same q-rows
        const int qrow = r0 + n;

        const short8_t bq0 = *(const short8_t*)(Q + (size_t)qrow * D_HEAD + quad * 8);
        const short8_t bq1 = *(const short8_t*)(Q + (size_t)qrow * D_HEAD + quad * 8 + 32);

        float m = -__builtin_inff();
        float l = 0.f;
        f32x4 o[4];
#pragma unroll
        for (int f = 0; f < 4; ++f) o[f] = (f32x4){0.f, 0.f, 0.f, 0.f};

        const int nrounds = (qb + 2) >> 1;     // ceil((qb+1)/2)
        for (int rd = 0; rd < nrounds; ++rd) {
            const int tg = rd * 2 + g;         // this group's tile
            const bool have = (tg <= qb);
            const int j0 = tg * 64;

            __syncthreads();                   // prior LDS reads done
            if (have) {
                GLD_LDS16(gK0 + j0 * 64, lK0);
                GLD_LDS16(gK1 + j0 * 64, lK1);
            }
            __syncthreads();                   // vmcnt drained by barrier

            if (!have) continue;               // idle group still hit barriers

            // ---- issue V global loads EARLY: latency hides under QK+SM ----
            short8_t va0[4], va1[4];
#pragma unroll
            for (int f = 0; f < 4; ++f) {
                const short* p = vbase + (size_t)(f * 16) * S_LEN + j0;
                va0[f] = *(const short8_t*)(p);
                va1[f] = *(const short8_t*)(p + 32);
            }

            // ---- S^T = K_tile . Q^T (Q pre-scaled by log2e/8) ----
            f32x4 st[4];
            __builtin_amdgcn_s_setprio(1);
#pragma unroll
            for (int kg = 0; kg < 4; ++kg) {
                const int rbase = (kg * 16 + n) * 64;
                const short8_t a0 = *(const short8_t*)&Ks[g][rbase + pcK];
                const short8_t a1 = *(const short8_t*)&Ks[g][rbase + (pcK ^ 32)];
                f32x4 acc = (f32x4){0.f, 0.f, 0.f, 0.f};
                acc = __builtin_amdgcn_mfma_f32_16x16x32_bf16(a0, bq0, acc, 0, 0, 0);
                acc = __builtin_amdgcn_mfma_f32_16x16x32_bf16(a1, bq1, acc, 0, 0, 0);
                st[kg] = acc;
            }
            __builtin_amdgcn_s_setprio(0);

            // ---- online softmax in exp2 domain (mask only on diagonal) ----
            float p[16];
            float mx = -__builtin_inff();
            if (tg == qb) {
#pragma unroll
                for (int kg = 0; kg < 4; ++kg)
#pragma unroll
                    for (int r = 0; r < 4; ++r) {
                        const int key = j0 + kg * 16 + quad * 4 + r;
                        float s = st[kg][r];
                        s = (key <= qrow) ? s : -__builtin_inff();
                        p[kg * 4 + r] = s;
                        mx = fmaxf(mx, s);
                    }
            } else {
#pragma unroll
                for (int i = 0; i < 16; ++i) {
                    const float s = st[i >> 2][i & 3];
                    p[i] = s;
                    mx = fmaxf(mx, s);
                }
            }
            mx = fmaxf(mx, __shfl_xor(mx, 16));
            mx = fmaxf(mx, __shfl_xor(mx, 32));

            float ls = 0.f;
            if (__all(mx <= m + 8.0f)) {
                // defer-max: keep old m, no rescale. P bounded by 2^8.
#pragma unroll
                for (int i = 0; i < 16; ++i) {
                    p[i] = __builtin_amdgcn_exp2f(p[i] - m);
                    ls += p[i];
                }
                ls += __shfl_xor(ls, 16);
                ls += __shfl_xor(ls, 32);
                l += ls;
            } else {
                const float mnew  = fmaxf(m, mx);
                const float alpha = __builtin_amdgcn_exp2f(m - mnew);
#pragma unroll
                for (int i = 0; i < 16; ++i) {
                    p[i] = __builtin_amdgcn_exp2f(p[i] - mnew);
                    ls += p[i];
                }
                ls += __shfl_xor(ls, 16);
                ls += __shfl_xor(ls, 32);
                l = l * alpha + ls;
                m = mnew;
#pragma unroll
                for (int f = 0; f < 4; ++f) {
                    o[f][0] *= alpha; o[f][1] *= alpha;
                    o[f][2] *= alpha; o[f][3] *= alpha;
                }
            }

            // ---- pack P -> bf16 by truncation, same-wave LDS round trip ----
#pragma unroll
            for (int kg = 0; kg < 4; ++kg) {
                const unsigned int b0 = __builtin_bit_cast(unsigned int, p[kg * 4 + 0]);
                const unsigned int b1 = __builtin_bit_cast(unsigned int, p[kg * 4 + 1]);
                const unsigned int b2 = __builtin_bit_cast(unsigned int, p[kg * 4 + 2]);
                const unsigned int b3 = __builtin_bit_cast(unsigned int, p[kg * 4 + 3]);
                uint2 pk;
                pk.x = (b0 >> 16) | (b1 & 0xffff0000u);
                pk.y = (b2 >> 16) | (b3 & 0xffff0000u);
                *(uint2*)&Ps[w][n][kg * 16 + quad * 4] = pk;
            }
            const short8_t pb0 = *(const short8_t*)&Ps[w][n][quad * 8];
            const short8_t pb1 = *(const short8_t*)&Ps[w][n][quad * 8 + 32];

            // ---- O^T += V^T_tile . P^T (V frags from global, pre-issued) ----
            __builtin_amdgcn_s_setprio(1);
#pragma unroll
            for (int f = 0; f < 4; ++f) {
                o[f] = __builtin_amdgcn_mfma_f32_16x16x32_bf16(va0[f], pb0, o[f], 0, 0, 0);
                o[f] = __builtin_amdgcn_mfma_f32_16x16x32_bf16(va1[f], pb1, o[f], 0, 0, 0);
            }
            __builtin_amdgcn_s_setprio(0);
        }

        // ---- merge the two group partials (flash-decoding combine) ----
        __syncthreads();   // all K-buffer LDS reads done
        // group 0 partial -> Ks area (16 KB f32), group 1 -> Vs area.
        // wave region wl*1024 floats; row n, logical chunk c at pc = c^n.
        {
            float* Og = (float*)(g == 0 ? (void*)Ks : (void*)Vs) + wl * 1024;
#pragma unroll
            for (int f = 0; f < 4; ++f) {
                const int c  = f * 4 + quad;
                const int pc = c ^ n;
                *(f32x4*)&Og[n * 64 + pc * 4] = o[f];   // raw partial (no 1/l)
            }
            if (quad == 0) {
                Ml[g][wl * 16 + n] = m;
                Ll[g][wl * 16 + n] = l;
            }
        }
        __syncthreads();
        // combine + store: thread t handles (row = t>>3, 8-float chunk c8 = t&7)
        {
            const int row = t >> 3;              // 0..63
            const int c8  = t & 7;               // 0..7
            const int wr  = row >> 4;            // owning wave region
            const int nr_ = row & 15;
            const float m0 = Ml[0][row], m1 = Ml[1][row];
            const float l0 = Ll[0][row], l1 = Ll[1][row];
            const float M  = fmaxf(m0, m1);
            const float a0 = __builtin_amdgcn_exp2f(m0 - M);
            const float a1 = __builtin_amdgcn_exp2f(m1 - M);
            const float inv = 1.0f / (l0 * a0 + l1 * a1);
            const float* O0 = (const float*)Ks + wr * 1024;
            const float* O1 = (const float*)Vs + wr * 1024;
            float* op = out + ((size_t)(bb * S_LEN + qb * 64 + row)) * D_MODEL
                        + hh * D_HEAD + c8 * 8;
#pragma unroll
            for (int cc = 0; cc < 2; ++cc) {
                const int c  = c8 * 2 + cc;      // logical chunk 0..15
                const int pc = c ^ nr_;
                const f32x4 x0 = *(const f32x4*)&O0[nr_ * 64 + pc * 4];
                const f32x4 x1 = *(const f32x4*)&O1[nr_ * 64 + pc * 4];
                f32x4 r;
                r[0] = (x0[0] * a0 + x1[0] * a1) * inv;
                r[1] = (x0[1] * a0 + x1[1] * a1) * inv;
                r[2] = (x0[2] * a0 + x1[2] * a1) * inv;
                r[3] = (x0[3] * a0 + x1[3] * a1) * inv;
                *(f32x4*)(op + cc * 4) = r;
            }
        }
        // next pass's first round begins with __syncthreads -> safe to restage
    }
}

// ---------------------------------------------------------------------------
extern "C" void kernel_launch(void* const* d_in, const int* in_sizes, int n_in,
                              void* d_out, int out_size, void* d_ws, size_t ws_size,
                              hipStream_t stream) {
    const float* x  = (const float*)d_in[0];
    const float* Wq = (const float*)d_in[1];
    const float* Wk = (const float*)d_in[2];
    const float* Wv = (const float*)d_in[3];
    float* out = (float*)d_out;

    // workspace: xb (8MB) | wt (6MB) | qkv (24MB) = 38MB
    short* xb  = (short*)d_ws;
    short* wt  = xb + MAT_ELEMS;
    short* qkv = wt + 3 * W_ELEMS;

    convert_x_kernel<<<dim3(MAT_ELEMS / (256 * 8)), 256, 0, stream>>>(x, xb);
    transpose_w_kernel<<<dim3(16, 16, 3), 256, 0, stream>>>(Wq, Wk, Wv, wt);

    qkv_mfma_gemm_kernel<<<dim3(32, 8, 3), 256, 0, stream>>>(xb, wt, qkv);

    attn_mfma_kernel<<<dim3(2 * N_HEADS, 16), 512, 0, stream>>>(qkv, out);
}

// Round 13
// 149.501 us; speedup vs baseline: 1.3292x; 1.3292x over previous
//
#include <hip/hip_runtime.h>
#include <hip/hip_bf16.h>

// B=2, S=2048, D=1024, H=16, DH=64. fp32 in/out; bf16 MFMA internals.
#define S_LEN   2048
#define D_MODEL 1024
#define N_HEADS 16
#define D_HEAD  64
#define HEAD_ELEMS (2048ull * 64ull)          // elements per (b,h) plane
#define MAT_ELEMS  (4096ull * 1024ull)        // one projected matrix (Q/K/V)
#define W_ELEMS    (1024ull * 1024ull)        // one weight matrix

typedef __attribute__((ext_vector_type(8))) short short8_t;   // 8 bf16
typedef __attribute__((ext_vector_type(4))) short short4_t;   // 4 bf16
typedef __attribute__((ext_vector_type(4))) float f32x4;      // MFMA C/D frag

__device__ __forceinline__ short f2bf(float f) {
    __hip_bfloat16 h = __float2bfloat16(f);
    union { __hip_bfloat16 h; short s; } cv;
    cv.h = h;
    return cv.s;
}

// global_load_lds width=16: LDS dest = wave-uniform base + lane*16
#define GLD_LDS16(gptr, lptr) \
    __builtin_amdgcn_global_load_lds( \
        (const __attribute__((address_space(1))) unsigned int*)(gptr), \
        (__attribute__((address_space(3))) unsigned int*)(lptr), 16, 0, 0)

// ---------------------------------------------------------------------------
// Kernel 0a: convert x fp32 -> bf16.
// ---------------------------------------------------------------------------
__global__ __launch_bounds__(256) void convert_x_kernel(
    const float* __restrict__ x, short* __restrict__ xb)
{
    const int i = (blockIdx.x * 256 + threadIdx.x) * 8;
    const float4 v0 = *(const float4*)(x + i);
    const float4 v1 = *(const float4*)(x + i + 4);
    short8_t u;
    u[0] = f2bf(v0.x); u[1] = f2bf(v0.y); u[2] = f2bf(v0.z); u[3] = f2bf(v0.w);
    u[4] = f2bf(v1.x); u[5] = f2bf(v1.y); u[6] = f2bf(v1.z); u[7] = f2bf(v1.w);
    *(short8_t*)(xb + i) = u;
}

// ---------------------------------------------------------------------------
// Kernel 0b: convert + transpose W fp32[k][n] -> bf16 Wt[n][k].
// ---------------------------------------------------------------------------
__global__ __launch_bounds__(256) void transpose_w_kernel(
    const float* __restrict__ Wq, const float* __restrict__ Wk,
    const float* __restrict__ Wv, short* __restrict__ wt)
{
    const int k0 = blockIdx.x * 64;
    const int n0 = blockIdx.y * 64;
    const int which = blockIdx.z;
    const float* W = (which == 0) ? Wq : (which == 1) ? Wk : Wv;
    short* out = wt + (size_t)which * W_ELEMS;

    __shared__ float Ts[64][68];   // [n_local][k_local]
    const int t = threadIdx.x;
    {
        const int c4 = (t & 15) * 4;
#pragma unroll
        for (int i = 0; i < 4; ++i) {
            const int r = (t >> 4) + i * 16;
            const float4 v = *(const float4*)(W + (size_t)(k0 + r) * D_MODEL + n0 + c4);
            Ts[c4 + 0][r] = v.x; Ts[c4 + 1][r] = v.y;
            Ts[c4 + 2][r] = v.z; Ts[c4 + 3][r] = v.w;
        }
    }
    __syncthreads();
    const int nl = t >> 2;
#pragma unroll
    for (int s = 0; s < 2; ++s) {
        const int koff = (t & 3) * 8 + s * 32;
        short8_t u;
#pragma unroll
        for (int j = 0; j < 8; ++j) u[j] = f2bf(Ts[nl][koff + j]);
        *(short8_t*)(out + (size_t)(n0 + nl) * D_MODEL + k0 + koff) = u;
    }
}

// ---------------------------------------------------------------------------
// Kernel 1: QKV GEMM (m97 structure). Q pre-scaled by (1/8)*log2(e) so the
// attention softmax can run in exp2 domain. Q/K epilogue round-trips through
// wave-private LDS for coalesced dwordx4 stores; V epilogue likewise
// ([dh][s] layout, pad 72) so its stores are 8 x dwordx4 along contiguous s.
// ---------------------------------------------------------------------------
__global__ __launch_bounds__(256, 3) void qkv_mfma_gemm_kernel(
    const short* __restrict__ xb,
    const short* __restrict__ wt,
    short* __restrict__ qkv)
{
    const int mBlock = blockIdx.x * 128;
    const int nBlock = blockIdx.y * 128;
    const int which  = blockIdx.z;
    const short* Bt = wt + (size_t)which * W_ELEMS;
    short* outBase  = qkv + (size_t)which * MAT_ELEMS;

    __shared__ short As[128 * 32];               // [m][k] contiguous, 8 KB
    __shared__ short Bs[128 * 32];               // [n][k] contiguous, 8 KB
    __shared__ __align__(16) short Es[4][64 * 72]; // per-wave epilogue, 36 KB

    const int t    = threadIdx.x;
    const int w    = t >> 6;
    const int lane = t & 63;
    const int n16  = lane & 15;
    const int quad = lane >> 4;
    const int mq   = (w & 1) * 64;
    const int nq   = (w >> 1) * 64;

    f32x4 acc[4][4];
#pragma unroll
    for (int i = 0; i < 4; ++i)
#pragma unroll
        for (int j = 0; j < 4; ++j) acc[i][j] = (f32x4){0.f, 0.f, 0.f, 0.f};

    const int off0 = w * 2048 + lane * 16;       // bytes
    const int off1 = off0 + 1024;
    const int r0s = off0 >> 6, k0s = (off0 & 63) >> 1;
    const int r1s = off1 >> 6, k1s = (off1 & 63) >> 1;
    const short* gA0 = xb + (size_t)(mBlock + r0s) * D_MODEL + k0s;
    const short* gA1 = xb + (size_t)(mBlock + r1s) * D_MODEL + k1s;
    const short* gB0 = Bt + (size_t)(nBlock + r0s) * D_MODEL + k0s;
    const short* gB1 = Bt + (size_t)(nBlock + r1s) * D_MODEL + k1s;
    short* lA0 = As + w * 1024;
    short* lA1 = As + w * 1024 + 512;
    short* lB0 = Bs + w * 1024;
    short* lB1 = Bs + w * 1024 + 512;

    for (int k0 = 0; k0 < D_MODEL; k0 += 32) {
        __syncthreads();
        GLD_LDS16(gA0 + k0, lA0);
        GLD_LDS16(gA1 + k0, lA1);
        GLD_LDS16(gB0 + k0, lB0);
        GLD_LDS16(gB1 + k0, lB1);
        __syncthreads();

        short8_t af[4], bf[4];
#pragma unroll
        for (int mt = 0; mt < 4; ++mt)
            af[mt] = *(const short8_t*)&As[(mq + mt * 16 + n16) * 32 + quad * 8];
#pragma unroll
        for (int nt = 0; nt < 4; ++nt)
            bf[nt] = *(const short8_t*)&Bs[(nq + nt * 16 + n16) * 32 + quad * 8];
#pragma unroll
        for (int mt = 0; mt < 4; ++mt)
#pragma unroll
            for (int nt = 0; nt < 4; ++nt)
                acc[mt][nt] = __builtin_amdgcn_mfma_f32_16x16x32_bf16(
                    af[mt], bf[nt], acc[mt][nt], 0, 0, 0);
    }

    // fold 1/sqrt(DH) AND log2(e) into Q (softmax runs in exp2 domain)
    const float oscale = (which == 0) ? 0.125f * 1.44269504089f : 1.0f;
    short* E = &Es[w][0];
    const int h  = (nBlock + nq) >> 6;           // head: fixed per wave tile
    const int m0 = mBlock + mq;                  // 64-aligned
    const int bb = m0 >> 11, ss0 = m0 & 2047;    // tile never crosses b
    const int rsub = lane >> 3;                  // 0..7
    const int ch   = lane & 7;                   // 0..7 (16B chunk)

    if (which < 2) {
        // ---- stage bf16 tile in wave-private LDS [s_local][dh], pad 72 ----
#pragma unroll
        for (int mt = 0; mt < 4; ++mt)
#pragma unroll
            for (int nt = 0; nt < 4; ++nt) {
                const int dhl = nt * 16 + n16;
#pragma unroll
                for (int reg = 0; reg < 4; ++reg) {
                    const int ml = mt * 16 + quad * 4 + reg;
                    E[ml * 72 + dhl] = f2bf(acc[mt][nt][reg] * oscale);
                }
            }
        // wave-private: no barrier needed; lgkmcnt orders write->read
        short* orow = outBase + ((size_t)(bb * N_HEADS + h) * S_LEN + ss0) * D_HEAD
                      + ch * 8;
#pragma unroll
        for (int it = 0; it < 8; ++it) {
            const int row = it * 8 + rsub;       // s_local
            const short8_t v = *(const short8_t*)&E[row * 72 + ch * 8];
            *(short8_t*)(orow + (size_t)row * D_HEAD) = v;
        }
    } else {
        // ---- V transposed (b,h,dh,s): stage [dh_local][s_local], pad 72 ----
#pragma unroll
        for (int mt = 0; mt < 4; ++mt)
#pragma unroll
            for (int nt = 0; nt < 4; ++nt) {
                const int dhl = nt * 16 + n16;
                const int sl0 = mt * 16 + quad * 4;
                short4_t u;
                u[0] = f2bf(acc[mt][nt][0]); u[1] = f2bf(acc[mt][nt][1]);
                u[2] = f2bf(acc[mt][nt][2]); u[3] = f2bf(acc[mt][nt][3]);
                *(short4_t*)&E[dhl * 72 + sl0] = u;
            }
        // coalesced: 8 lanes x 16B = 128B contiguous in s per dh-row
        short* orow = outBase + ((size_t)(bb * N_HEADS + h) * D_HEAD) * S_LEN
                      + ss0 + ch * 8;
#pragma unroll
        for (int it = 0; it < 8; ++it) {
            const int dhl = it * 8 + rsub;       // dh_local 0..63
            const short8_t v = *(const short8_t*)&E[dhl * 72 + ch * 8];
            *(short8_t*)(orow + (size_t)dhl * S_LEN) = v;
        }
    }
}

// ---------------------------------------------------------------------------
// Kernel 2: causal flash attention via bf16 MFMA, v7 (verified optimum).
// Session model (12 variants): every correct structure lands at ~66 staged
// tiles/CU x ~1.6k cy DS-pipe time ≈ 44 µs — the DS pipe is the saturated
// per-CU resource. Escapes tried and rejected: no-staging (v5/v15: L2 miss +
// latency exposure), in-lane P via mfma16 (v14: b64 V-read bank conflicts
// cancel the gain; v13 asm miscompile), key-split (v10 spill, v11 lockstep),
// 32x32 QBLK=32 (v16: unverified A/B fragment layout, correctness fail).
// v7: 512 threads = TWO independent 4-wave groups; per round, group g
// stages+computes tile 2*round+g into its own Ks/Vs buffers. Partials merged
// flash-decoding-style at pass end. Keeps: XOR-swizzled K/V staging via
// global_load_lds, exp2-domain softmax (log2e/8 folded into Q by the GEMM),
// defer-max (T13), setprio (T5), paired LPT grid (32 bh x 16 pairs).
// ---------------------------------------------------------------------------
__global__ __launch_bounds__(512, 4) void attn_mfma_kernel(
    const short* __restrict__ qkv,
    float* __restrict__ out)
{
    const int bh   = blockIdx.x;
    const int pr   = blockIdx.y;          // pair index 0..15
    const int t    = threadIdx.x;         // 0..511
    const int w    = t >> 6;              // 0..7
    const int g    = w >> 2;              // tile-group 0/1
    const int wl   = w & 3;               // wave-in-group 0..3
    const int lane = t & 63;
    const int n    = lane & 15;
    const int quad = lane >> 4;

    const short* Q  = qkv + (size_t)bh * HEAD_ELEMS;
    const short* K  = qkv + MAT_ELEMS + (size_t)bh * HEAD_ELEMS;
    const short* Vt = qkv + 2 * MAT_ELEMS + (size_t)bh * HEAD_ELEMS;  // (dh,s)

    __shared__ __align__(16) short Ks[2][64 * 64];       // per-group K, 16 KB
    __shared__ __align__(16) short Vs[2][64 * 64];       // per-group V, 16 KB
    __shared__ __align__(16) short Ps[8][16][72];        // per-wave P round-trip
    __shared__ float Ml[2][64];                          // per-group m partial
    __shared__ float Ll[2][64];                          // per-group l partial

    // --- staging: group-wave wl stages rows [16wl,16wl+16) of K and V ---
    const int srow0 = wl * 16 + (lane >> 3);             // inst-0 row
    const int srow1 = srow0 + 8;                         // inst-1 row
    const int sd0 = ((lane & 7) ^ (srow0 & 7)) * 8;      // swizzled src offset
    const int sd1 = ((lane & 7) ^ (srow1 & 7)) * 8;
    const short* gK0 = K + srow0 * 64 + sd0;             // += j0*64 per tile
    const short* gK1 = K + srow1 * 64 + sd1;
    const short* gV0 = Vt + (size_t)srow0 * S_LEN + sd0; // += j0 per tile
    const short* gV1 = Vt + (size_t)srow1 * S_LEN + sd1;
    short* lK0 = &Ks[g][(wl * 16) * 64];
    short* lK1 = &Ks[g][(wl * 16 + 8) * 64];
    short* lV0 = &Vs[g][(wl * 16) * 64];
    short* lV1 = &Vs[g][(wl * 16 + 8) * 64];

    // frag-read physical chunk offset (shorts): a0 at pcK, a1 at pcK^32
    const int pcK = ((quad ^ (n & 7))) * 8;

    const int bb = bh >> 4;
    const int hh = bh & 15;

    for (int pass = 0; pass < 2; ++pass) {
        const int qb = pass ? (31 - pr) : pr;
        const int r0 = qb * 64 + wl * 16;      // both groups cover same q-rows
        const int qrow = r0 + n;

        const short8_t bq0 = *(const short8_t*)(Q + (size_t)qrow * D_HEAD + quad * 8);
        const short8_t bq1 = *(const short8_t*)(Q + (size_t)qrow * D_HEAD + quad * 8 + 32);

        float m = -__builtin_inff();
        float l = 0.f;
        f32x4 o[4];
#pragma unroll
        for (int f = 0; f < 4; ++f) o[f] = (f32x4){0.f, 0.f, 0.f, 0.f};

        const int nrounds = (qb + 2) >> 1;     // ceil((qb+1)/2)
        for (int rd = 0; rd < nrounds; ++rd) {
            const int tg = rd * 2 + g;         // this group's tile
            const bool have = (tg <= qb);
            const int j0 = tg * 64;

            __syncthreads();                   // prior LDS reads done
            if (have) {
                GLD_LDS16(gK0 + j0 * 64, lK0);
                GLD_LDS16(gK1 + j0 * 64, lK1);
                GLD_LDS16(gV0 + j0, lV0);
                GLD_LDS16(gV1 + j0, lV1);
            }
            __syncthreads();                   // vmcnt drained by barrier

            if (!have) continue;               // idle group still hit barriers

            // ---- S^T = K_tile . Q^T (Q pre-scaled by log2e/8) ----
            f32x4 st[4];
            __builtin_amdgcn_s_setprio(1);
#pragma unroll
            for (int kg = 0; kg < 4; ++kg) {
                const int rbase = (kg * 16 + n) * 64;
                const short8_t a0 = *(const short8_t*)&Ks[g][rbase + pcK];
                const short8_t a1 = *(const short8_t*)&Ks[g][rbase + (pcK ^ 32)];
                f32x4 acc = (f32x4){0.f, 0.f, 0.f, 0.f};
                acc = __builtin_amdgcn_mfma_f32_16x16x32_bf16(a0, bq0, acc, 0, 0, 0);
                acc = __builtin_amdgcn_mfma_f32_16x16x32_bf16(a1, bq1, acc, 0, 0, 0);
                st[kg] = acc;
            }
            __builtin_amdgcn_s_setprio(0);

            // ---- online softmax in exp2 domain (mask only on diagonal) ----
            float p[16];
            float mx = -__builtin_inff();
            if (tg == qb) {
#pragma unroll
                for (int kg = 0; kg < 4; ++kg)
#pragma unroll
                    for (int r = 0; r < 4; ++r) {
                        const int key = j0 + kg * 16 + quad * 4 + r;
                        float s = st[kg][r];
                        s = (key <= qrow) ? s : -__builtin_inff();
                        p[kg * 4 + r] = s;
                        mx = fmaxf(mx, s);
                    }
            } else {
#pragma unroll
                for (int i = 0; i < 16; ++i) {
                    const float s = st[i >> 2][i & 3];
                    p[i] = s;
                    mx = fmaxf(mx, s);
                }
            }
            mx = fmaxf(mx, __shfl_xor(mx, 16));
            mx = fmaxf(mx, __shfl_xor(mx, 32));

            float ls = 0.f;
            if (__all(mx <= m + 8.0f)) {
                // defer-max: keep old m, no rescale. P bounded by 2^8.
#pragma unroll
                for (int i = 0; i < 16; ++i) {
                    p[i] = __builtin_amdgcn_exp2f(p[i] - m);
                    ls += p[i];
                }
                ls += __shfl_xor(ls, 16);
                ls += __shfl_xor(ls, 32);
                l += ls;
            } else {
                const float mnew  = fmaxf(m, mx);
                const float alpha = __builtin_amdgcn_exp2f(m - mnew);
#pragma unroll
                for (int i = 0; i < 16; ++i) {
                    p[i] = __builtin_amdgcn_exp2f(p[i] - mnew);
                    ls += p[i];
                }
                ls += __shfl_xor(ls, 16);
                ls += __shfl_xor(ls, 32);
                l = l * alpha + ls;
                m = mnew;
#pragma unroll
                for (int f = 0; f < 4; ++f) {
                    o[f][0] *= alpha; o[f][1] *= alpha;
                    o[f][2] *= alpha; o[f][3] *= alpha;
                }
            }

            // ---- pack P -> bf16 by truncation, same-wave LDS round trip ----
#pragma unroll
            for (int kg = 0; kg < 4; ++kg) {
                const unsigned int b0 = __builtin_bit_cast(unsigned int, p[kg * 4 + 0]);
                const unsigned int b1 = __builtin_bit_cast(unsigned int, p[kg * 4 + 1]);
                const unsigned int b2 = __builtin_bit_cast(unsigned int, p[kg * 4 + 2]);
                const unsigned int b3 = __builtin_bit_cast(unsigned int, p[kg * 4 + 3]);
                uint2 pk;
                pk.x = (b0 >> 16) | (b1 & 0xffff0000u);
                pk.y = (b2 >> 16) | (b3 & 0xffff0000u);
                *(uint2*)&Ps[w][n][kg * 16 + quad * 4] = pk;
            }
            const short8_t pb0 = *(const short8_t*)&Ps[w][n][quad * 8];
            const short8_t pb1 = *(const short8_t*)&Ps[w][n][quad * 8 + 32];

            // ---- O^T += V^T_tile . P^T ----
            __builtin_amdgcn_s_setprio(1);
#pragma unroll
            for (int f = 0; f < 4; ++f) {
                const int rbase = (f * 16 + n) * 64;
                const short8_t va0 = *(const short8_t*)&Vs[g][rbase + pcK];
                const short8_t va1 = *(const short8_t*)&Vs[g][rbase + (pcK ^ 32)];
                o[f] = __builtin_amdgcn_mfma_f32_16x16x32_bf16(va0, pb0, o[f], 0, 0, 0);
                o[f] = __builtin_amdgcn_mfma_f32_16x16x32_bf16(va1, pb1, o[f], 0, 0, 0);
            }
            __builtin_amdgcn_s_setprio(0);
        }

        // ---- merge the two group partials (flash-decoding combine) ----
        __syncthreads();   // all staging-buffer reads done
        // group 0 partial -> Ks area (16 KB f32), group 1 -> Vs area.
        // wave region wl*1024 floats; row n, logical chunk c at pc = c^n.
        {
            float* Og = (float*)(g == 0 ? (void*)Ks : (void*)Vs) + wl * 1024;
#pragma unroll
            for (int f = 0; f < 4; ++f) {
                const int c  = f * 4 + quad;
                const int pc = c ^ n;
                *(f32x4*)&Og[n * 64 + pc * 4] = o[f];   // raw partial (no 1/l)
            }
            if (quad == 0) {
                Ml[g][wl * 16 + n] = m;
                Ll[g][wl * 16 + n] = l;
            }
        }
        __syncthreads();
        // combine + store: thread t handles (row = t>>3, 8-float chunk c8 = t&7)
        {
            const int row = t >> 3;              // 0..63
            const int c8  = t & 7;               // 0..7
            const int wr  = row >> 4;            // owning wave region
            const int nr_ = row & 15;
            const float m0 = Ml[0][row], m1 = Ml[1][row];
            const float l0 = Ll[0][row], l1 = Ll[1][row];
            const float M  = fmaxf(m0, m1);
            const float a0 = __builtin_amdgcn_exp2f(m0 - M);
            const float a1 = __builtin_amdgcn_exp2f(m1 - M);
            const float inv = 1.0f / (l0 * a0 + l1 * a1);
            const float* O0 = (const float*)Ks + wr * 1024;
            const float* O1 = (const float*)Vs + wr * 1024;
            float* op = out + ((size_t)(bb * S_LEN + qb * 64 + row)) * D_MODEL
                        + hh * D_HEAD + c8 * 8;
#pragma unroll
            for (int cc = 0; cc < 2; ++cc) {
                const int c  = c8 * 2 + cc;      // logical chunk 0..15
                const int pc = c ^ nr_;
                const f32x4 x0 = *(const f32x4*)&O0[nr_ * 64 + pc * 4];
                const f32x4 x1 = *(const f32x4*)&O1[nr_ * 64 + pc * 4];
                f32x4 r;
                r[0] = (x0[0] * a0 + x1[0] * a1) * inv;
                r[1] = (x0[1] * a0 + x1[1] * a1) * inv;
                r[2] = (x0[2] * a0 + x1[2] * a1) * inv;
                r[3] = (x0[3] * a0 + x1[3] * a1) * inv;
                *(f32x4*)(op + cc * 4) = r;
            }
        }
        // next pass's first round begins with __syncthreads -> safe to restage
    }
}

// ---------------------------------------------------------------------------
extern "C" void kernel_launch(void* const* d_in, const int* in_sizes, int n_in,
                              void* d_out, int out_size, void* d_ws, size_t ws_size,
                              hipStream_t stream) {
    const float* x  = (const float*)d_in[0];
    const float* Wq = (const float*)d_in[1];
    const float* Wk = (const float*)d_in[2];
    const float* Wv = (const float*)d_in[3];
    float* out = (float*)d_out;

    // workspace: xb (8MB) | wt (6MB) | qkv (24MB) = 38MB
    short* xb  = (short*)d_ws;
    short* wt  = xb + MAT_ELEMS;
    short* qkv = wt + 3 * W_ELEMS;

    convert_x_kernel<<<dim3(MAT_ELEMS / (256 * 8)), 256, 0, stream>>>(x, xb);
    transpose_w_kernel<<<dim3(16, 16, 3), 256, 0, stream>>>(Wq, Wk, Wv, wt);

    qkv_mfma_gemm_kernel<<<dim3(32, 8, 3), 256, 0, stream>>>(xb, wt, qkv);

    attn_mfma_kernel<<<dim3(2 * N_HEADS, 16), 512, 0, stream>>>(qkv, out);
}